// Round 3
// baseline (232.762 us; speedup 1.0000x reference)
//
#include <hip/hip_runtime.h>

// ---------------------------------------------------------------------------
// GNNLoss. N=2048, C=512, D=128, K_POOL=1024, T=0.07, NEG=-10.
// Round 17: R16 structure (16 -> 11 dispatches) + staging-coverage FIX.
// R16 bug: B-operand LDS staging in k_hop_xt2/k_hop_norm/k_lin_pool covered
// only 16 of 32 K-columns (2 threads/row x 8 shorts) -> MFMA read uninit LDS
// -> NaN. Fix: two ulonglong2 loads per thread (16 cols), full 128x32 tile.
// - Full-K hop GEMMs (16x128 tiles, 256 blocks) own complete output rows:
//   reduce/combine fuse into the GEMM epilogue (shfl_xor row norm).
//   * k_hop_xt2  = hop1 + Xt2 build (transposed bf16 store via LDS).
//   * k_hop_norm = hop2 + hW0-add + bias + l2norm (+scores); reused pooled.
// - k_lin_pool gathers f_g[idx[p]]*vals[p] inline in A-staging.
// - Pooled NCE finalize rides as tail-block on pooled gram (fence+counter).
// Rules kept: no cross-WG sync; fp32 embed/gram path untouched.
// ---------------------------------------------------------------------------

#define TINV (1.0f / 0.07f)

using short8 = __attribute__((ext_vector_type(8))) short;
using f32x4  = __attribute__((ext_vector_type(4))) float;

__device__ __forceinline__ unsigned short f2bf(float f) {
    unsigned u = __float_as_uint(f);
    u += 0x7fff + ((u >> 16) & 1);
    return (unsigned short)(u >> 16);
}

// ---------------- fp32 64x64 tile core -------------------------------------
template<bool BT>
__device__ __forceinline__ void mm_tile(const float* __restrict__ A, int lda,
                                        const float* __restrict__ B, int ldb,
                                        int i0, int j0, int k0, int k1,
                                        float (&acc)[4][4],
                                        float (&As)[16][68], float (&Bs)[16][68])
{
    const int tid = threadIdx.x;
    const int tx = tid & 15;
    const int ty = tid >> 4;
    const int lr = tid >> 2;
    const int lc = (tid & 3) * 4;
    for (int k = k0; k < k1; k += 16) {
        float4 av = *(const float4*)(A + (size_t)(i0 + lr) * lda + (k + lc));
        As[lc + 0][lr] = av.x; As[lc + 1][lr] = av.y;
        As[lc + 2][lr] = av.z; As[lc + 3][lr] = av.w;
        if (BT) {
            float4 bv = *(const float4*)(B + (size_t)(j0 + lr) * ldb + (k + lc));
            Bs[lc + 0][lr] = bv.x; Bs[lc + 1][lr] = bv.y;
            Bs[lc + 2][lr] = bv.z; Bs[lc + 3][lr] = bv.w;
        } else {
            const int n = tid & 63;
            const int kb = tid >> 6;
#pragma unroll
            for (int it = 0; it < 4; ++it)
                Bs[kb * 4 + it][n] = B[(size_t)(k + kb * 4 + it) * ldb + (j0 + n)];
        }
        __syncthreads();
#pragma unroll
        for (int kk = 0; kk < 16; ++kk) {
            float a[4], b[4];
#pragma unroll
            for (int u = 0; u < 4; ++u) a[u] = As[kk][ty * 4 + u];
#pragma unroll
            for (int v = 0; v < 4; ++v) b[v] = Bs[kk][tx * 4 + v];
#pragma unroll
            for (int u = 0; u < 4; ++u)
#pragma unroll
                for (int v = 0; v < 4; ++v)
                    acc[u][v] = fmaf(a[u], b[v], acc[u][v]);
        }
        __syncthreads();
    }
}

// ---------------- bf16 MFMA 64x128 tile core (gram/NCE kernels) ------------
__device__ __forceinline__ void mm64x128(const unsigned short* __restrict__ Ab, int lda,
                                         const unsigned short* __restrict__ Bb, int ldb,
                                         int i0, int j0, int k0, int Kc,
                                         f32x4 (&acc)[8],
                                         unsigned short (&As)[64][40],
                                         unsigned short (&Bs)[128][40])
{
    const int tid = threadIdx.x;
    const int w = tid >> 6;
    const int lane = tid & 63;
    const int m = lane & 15;
    const int q = lane >> 4;
    const int ar = tid >> 2;
    const int ac = (tid & 3) * 8;
    for (int ks = 0; ks < Kc; ks += 32) {
        const int k = k0 + ks;
        *(ulonglong2*)&As[ar][ac] =
            *(const ulonglong2*)(Ab + (size_t)(i0 + ar) * lda + k + ac);
        *(ulonglong2*)&Bs[ar][ac] =
            *(const ulonglong2*)(Bb + (size_t)(j0 + ar) * ldb + k + ac);
        *(ulonglong2*)&Bs[ar + 64][ac] =
            *(const ulonglong2*)(Bb + (size_t)(j0 + ar + 64) * ldb + k + ac);
        __syncthreads();
        short8 a = *(const short8*)&As[w * 16 + m][q * 8];
#pragma unroll
        for (int nt = 0; nt < 8; ++nt) {
            short8 b = *(const short8*)&Bs[nt * 16 + m][q * 8];
            acc[nt] = __builtin_amdgcn_mfma_f32_16x16x32_bf16(a, b, acc[nt], 0, 0, 0);
        }
        __syncthreads();
    }
}

// ---------------- launch 1: embed GEMM + setup roles ----------------------
__launch_bounds__(256)
__global__ void k_setup_embed(const float* __restrict__ fs, const float* __restrict__ ft,
                              const float* __restrict__ W, float* __restrict__ part,
                              size_t zstr, int* __restrict__ zwords, int zcount,
                              float* __restrict__ out,
                              const float* __restrict__ Wg, const float* __restrict__ Wp,
                              unsigned short* __restrict__ Wtall)
{
    __shared__ float As[16][68];
    __shared__ float Bs[16][68];
    const int b = blockIdx.x;
    const int tid = threadIdx.x;
    if (b < 512) {
        const int z = b & 3;
        const int by = (b >> 2) & 63;
        const int bx = b >> 8;
        const float* A = (by < 32) ? ft : fs;
        const int i0 = (by & 31) * 64;
        const int j0 = bx * 64;
        float acc[4][4] = {};
        mm_tile<false>(A, 512, W, 128, i0, j0, z * 128, z * 128 + 128, acc, As, Bs);
        const int tx = tid & 15, ty = tid >> 4;
        float* dst = part + (size_t)z * zstr;
#pragma unroll
        for (int u = 0; u < 4; ++u) {
            const size_t ri = (size_t)(by * 64 + ty * 4 + u) * 128 + j0 + tx * 4;
            float4 vv;
            vv.x = acc[u][0]; vv.y = acc[u][1]; vv.z = acc[u][2]; vv.w = acc[u][3];
            *(float4*)(dst + ri) = vv;
        }
    } else if (b < 561) {
        const int i = (b - 512) * 256 + tid;
        if (i < zcount) zwords[i] = 0;
        if (b == 512 && tid == 0) out[0] = 0.0f;
    } else {
        const int e0 = (b - 561) * 2048 + tid;
#pragma unroll
        for (int it = 0; it < 8; ++it) {
            const int e = e0 + it * 256;
            const int c = e >> 14;
            const int rem = e & 16383;
            const int n = rem >> 7, k = rem & 127;
            const float* src = (c < 3) ? (Wg + (size_t)c * 16384)
                                       : (Wp + (size_t)(c - 3) * 16384);
            Wtall[e] = f2bf(src[(size_t)k * 128 + n]);
        }
    }
}

// ---------------- combine embed partials + bias + l2norm -------------------
__global__ void combine_norm(const float* __restrict__ part, int nz, size_t zstr,
                             const float* __restrict__ bias,
                             float* __restrict__ f32out,
                             unsigned short* __restrict__ bf16out)
{
    const int row = blockIdx.x;
    const int tid = threadIdx.x;                 // 128
    float v = bias[tid];
    for (int z = 0; z < nz; ++z) v += part[(size_t)z * zstr + (size_t)row * 128 + tid];
    __shared__ float red[128];
    red[tid] = v * v;
    __syncthreads();
    for (int s = 64; s > 0; s >>= 1) {
        if (tid < s) red[tid] += red[tid + s];
        __syncthreads();
    }
    const float o = v * (1.0f / sqrtf(red[0]));
    f32out[(size_t)row * 128 + tid] = o;
    bf16out[(size_t)row * 128 + tid] = f2bf(o);
}

// -------- fused gram + threshold + pack + (rider) 3x TAG-linear GEMMs ------
__launch_bounds__(256)
__global__ void k_gram_fused(const float* __restrict__ f_e,
                             unsigned short* __restrict__ A01,
                             unsigned long long* __restrict__ bits,
                             int* __restrict__ deg,
                             const unsigned short* __restrict__ feb,
                             const unsigned short* __restrict__ Wt,
                             float* __restrict__ hW)
{
    __shared__ __align__(16) unsigned char smem[15360];
    const int b = blockIdx.x;
    const int tid = threadIdx.x;
    if (b >= 528) {
        // rider: hW[z] = feb @ Wt[z]^T  (M=4096, N=128, K=128)
        unsigned short (&As2)[64][40]  = *reinterpret_cast<unsigned short(*)[64][40]>(smem);
        unsigned short (&Bs2)[128][40] = *reinterpret_cast<unsigned short(*)[128][40]>(smem + 5120);
        const int lb = b - 528;
        const int z = lb >> 6;
        const int i0 = (lb & 63) * 64;
        f32x4 acc[8];
#pragma unroll
        for (int t = 0; t < 8; ++t)
#pragma unroll
            for (int r = 0; r < 4; ++r) acc[t][r] = 0.0f;
        mm64x128(feb, 128, Wt + (size_t)z * 16384, 128, i0, 0, 0, 128, acc, As2, Bs2);
        const int w = tid >> 6, lane = tid & 63, m = lane & 15, q = lane >> 4;
        float* Cb = hW + (size_t)z * (4096ull * 128);
#pragma unroll
        for (int nt = 0; nt < 8; ++nt) {
            const int col = nt * 16 + m;
#pragma unroll
            for (int r = 0; r < 4; ++r) {
                const int row = i0 + w * 16 + q * 4 + r;
                Cb[(size_t)row * 128 + col] = acc[nt][r];
            }
        }
        return;
    }
    float (&As)[16][68] = *reinterpret_cast<float(*)[16][68]>(smem);
    float (&Bs)[16][68] = *reinterpret_cast<float(*)[16][68]>(smem + 4352);
    unsigned char (&nib)[64][16]  = *reinterpret_cast<unsigned char(*)[64][16]>(smem + 8704);
    unsigned char (&nibT)[64][16] = *reinterpret_cast<unsigned char(*)[64][16]>(smem + 9728);
    unsigned long long (&chk)[64]  = *reinterpret_cast<unsigned long long(*)[64]>(smem + 10752);
    unsigned long long (&chkT)[64] = *reinterpret_cast<unsigned long long(*)[64]>(smem + 11264);
    int by = (int)((sqrtf(8.0f * b + 1.0f) - 1.0f) * 0.5f);
    while ((by + 1) * (by + 2) / 2 <= b) ++by;
    while (by * (by + 1) / 2 > b) --by;
    const int bx = b - by * (by + 1) / 2;
    const int i0 = by * 64, j0 = bx * 64;
    float acc[4][4] = {};
    mm_tile<true>(f_e, 128, f_e, 128, i0, j0, 0, 128, acc, As, Bs);
    const int tx = tid & 15, ty = tid >> 4;
    unsigned pb = 0;
#pragma unroll
    for (int u = 0; u < 4; ++u)
#pragma unroll
        for (int v = 0; v < 4; ++v) {
            bool pred = (acc[u][v] > 0.0f) || (i0 + ty * 4 + u == j0 + tx * 4 + v);
            pb |= (unsigned)pred << (u * 4 + v);
        }
#pragma unroll
    for (int u = 0; u < 4; ++u) nib[ty * 4 + u][tx] = (pb >> (4 * u)) & 15;
#pragma unroll
    for (int v = 0; v < 4; ++v) {
        unsigned nt = 0;
#pragma unroll
        for (int u = 0; u < 4; ++u) nt |= ((pb >> (u * 4 + v)) & 1u) << u;
        nibT[tx * 4 + v][ty] = nt;
    }
    __syncthreads();
    if (tid < 64) {
        unsigned long long c = 0;
#pragma unroll
        for (int t = 0; t < 16; ++t) c |= (unsigned long long)nib[tid][t] << (4 * t);
        chk[tid] = c;
        bits[(size_t)(i0 + tid) * 32 + (j0 >> 6)] = c;
        atomicAdd(&deg[i0 + tid], __popcll(c));
    } else if (tid < 128 && bx != by) {
        const int r = tid - 64;
        unsigned long long c = 0;
#pragma unroll
        for (int t = 0; t < 16; ++t) c |= (unsigned long long)nibT[r][t] << (4 * t);
        chkT[r] = c;
        bits[(size_t)(j0 + r) * 32 + (i0 >> 6)] = c;
        atomicAdd(&deg[j0 + r], __popcll(c));
    }
    __syncthreads();
    // packed 8B stores: 4 iters x (16 rows x 16 col-groups of 4)
#pragma unroll
    for (int it = 0; it < 4; ++it) {
        const int row = it * 16 + (tid >> 4);
        const int c0 = (tid & 15) * 4;
        unsigned short o[4];
#pragma unroll
        for (int c = 0; c < 4; ++c)
            o[c] = ((chk[row] >> (c0 + c)) & 1) ? (unsigned short)0x3F80 : (unsigned short)0;
        *(ulonglong1*)&A01[(size_t)(i0 + row) * 2048 + j0 + c0] = *(ulonglong1*)o;
        if (bx != by) {
            unsigned short o2[4];
#pragma unroll
            for (int c = 0; c < 4; ++c)
                o2[c] = ((chkT[row] >> (c0 + c)) & 1) ? (unsigned short)0x3F80 : (unsigned short)0;
            *(ulonglong1*)&A01[(size_t)(j0 + row) * 2048 + i0 + c0] = *(ulonglong1*)o2;
        }
    }
}

// ------------- Xt1[n][i] = hW2[(branch)i][n&127] / sqrt(deg[i]) ------------
__global__ void make_xt(const float* __restrict__ src, const int* __restrict__ deg,
                        unsigned short* __restrict__ xt, float* __restrict__ dinv)
{
    __shared__ float T[32][33];
    const int b = blockIdx.x;                    // 512 = 8 x 64
    const int bx = b & 7, by = b >> 3;
    const int tid = threadIdx.x;                 // 256
    const int iloc = tid >> 3, nq = (tid & 7) * 4;
    const int n0 = bx * 32;
    const int i = by * 32 + iloc;
    const int srow = (n0 >= 128 ? 2048 : 0) + i;
    float4 f = *(const float4*)(src + (size_t)srow * 128 + ((n0 + nq) & 127));
    const float d = 1.0f / sqrtf((float)deg[i]);
    if (bx == 0 && (tid & 7) == 0) dinv[i] = d;
    T[nq + 0][iloc] = f.x * d; T[nq + 1][iloc] = f.y * d;
    T[nq + 2][iloc] = f.z * d; T[nq + 3][iloc] = f.w * d;
    __syncthreads();
    const int nloc = tid >> 3, ic = (tid & 7) * 4;
    unsigned short o[4];
#pragma unroll
    for (int c = 0; c < 4; ++c) o[c] = f2bf(T[nloc][ic + c]);
    *(ulonglong1*)(xt + (size_t)(n0 + nloc) * 2048 + by * 32 + ic) = *(ulonglong1*)o;
}

// ---- hop1 fused: Y1 = A01 @ Xt1 (full K), Xt2 = (hW1 + d*Y1)*d transposed --
__launch_bounds__(256)
__global__ void k_hop_xt2(const unsigned short* __restrict__ A,   // [2048][2048]
                          const unsigned short* __restrict__ X,   // Xt1 [256][2048]
                          const float* __restrict__ dinv,
                          const float* __restrict__ hW1,          // [4096][128]
                          unsigned short* __restrict__ xt2)       // [256][2048]
{
    __shared__ unsigned short As[16][40];
    __shared__ unsigned short Bs[128][40];
    __shared__ unsigned short T[128][24];
    __shared__ float sd[16];
    const int tid = threadIdx.x;
    const int bx = blockIdx.x;                   // n-half (0=teacher,1=student)
    const int i0 = blockIdx.y * 16;
    const int j0 = bx * 128;
    const int w = tid >> 6, lane = tid & 63, m = lane & 15, q = lane >> 4;
    if (tid < 16) sd[tid] = dinv[i0 + tid];
    const int aru = tid >> 4, acu = (tid & 15) * 2;
    const int br = tid >> 1, bc = (tid & 1) * 16;
    const unsigned short* Apt = A + (size_t)(i0 + aru) * 2048 + acu;
    const unsigned short* Bpt = X + (size_t)(j0 + br) * 2048 + bc;
    unsigned aReg = *(const unsigned*)Apt;
    ulonglong2 bReg0 = *(const ulonglong2*)Bpt;
    ulonglong2 bReg1 = *(const ulonglong2*)(Bpt + 8);
    f32x4 acc[2];
#pragma unroll
    for (int t = 0; t < 2; ++t)
#pragma unroll
        for (int r = 0; r < 4; ++r) acc[t][r] = 0.0f;
    for (int ks = 0; ks < 2048; ks += 32) {
        *(unsigned*)&As[aru][acu] = aReg;
        *(ulonglong2*)&Bs[br][bc] = bReg0;
        *(ulonglong2*)&Bs[br][bc + 8] = bReg1;
        __syncthreads();
        if (ks + 32 < 2048) {
            aReg = *(const unsigned*)(Apt + ks + 32);
            bReg0 = *(const ulonglong2*)(Bpt + ks + 32);
            bReg1 = *(const ulonglong2*)(Bpt + ks + 32 + 8);
        }
        short8 a = *(const short8*)&As[m][q * 8];
#pragma unroll
        for (int nt = 0; nt < 2; ++nt) {
            short8 bb = *(const short8*)&Bs[w * 32 + nt * 16 + m][q * 8];
            acc[nt] = __builtin_amdgcn_mfma_f32_16x16x32_bf16(a, bb, acc[nt], 0, 0, 0);
        }
        __syncthreads();
    }
#pragma unroll
    for (int nt = 0; nt < 2; ++nt) {
        const int nl = w * 32 + nt * 16 + m;
        const int n = j0 + nl;
        const size_t boff = (n >= 128) ? 2048 : 0;
#pragma unroll
        for (int r = 0; r < 4; ++r) {
            const int il = q * 4 + r;
            const float d = sd[il];
            const float hv = hW1[(boff + i0 + il) * 128 + (n & 127)];
            T[nl][il] = f2bf((hv + d * acc[nt][r]) * d);
        }
    }
    __syncthreads();
    const int nl2 = tid >> 1, ic = (tid & 1) * 8;
    *(ulonglong2*)(xt2 + (size_t)(j0 + nl2) * 2048 + i0 + ic) =
        *(const ulonglong2*)&T[nl2][ic];
}

// ---- hop2/pooled fused: Y = A @ X (full K), out = l2norm(add + bias + d*Y)
// ---- (+ optional pooling scores on the teacher half) ----------------------
__launch_bounds__(256)
__global__ void k_hop_norm(const unsigned short* __restrict__ A, int Kc, // lda=ldb=M=Kc
                           const unsigned short* __restrict__ X,        // [256][Kc]
                           const float* __restrict__ addP,              // [2M][128]
                           const float* __restrict__ bias,
                           const float* __restrict__ dinvf,
                           const int* __restrict__ degi,
                           float* __restrict__ f32out,
                           unsigned short* __restrict__ bf16out,
                           const float* __restrict__ Wp, const float* __restrict__ bp,
                           float* __restrict__ scores)
{
    __shared__ unsigned short As[16][40];
    __shared__ unsigned short Bs[128][40];
    __shared__ float sd[16];
    __shared__ float redA[4][16];
    __shared__ float redB[4][16];
    const int tid = threadIdx.x;
    const int bx = blockIdx.x;                   // branch
    const int i0 = blockIdx.y * 16;
    const int j0 = bx * 128;
    const int w = tid >> 6, lane = tid & 63, m = lane & 15, q = lane >> 4;
    if (tid < 16) sd[tid] = degi ? rsqrtf((float)degi[i0 + tid]) : dinvf[i0 + tid];
    const int aru = tid >> 4, acu = (tid & 15) * 2;
    const int br = tid >> 1, bc = (tid & 1) * 16;
    const unsigned short* Apt = A + (size_t)(i0 + aru) * Kc + acu;
    const unsigned short* Bpt = X + (size_t)(j0 + br) * Kc + bc;
    unsigned aReg = *(const unsigned*)Apt;
    ulonglong2 bReg0 = *(const ulonglong2*)Bpt;
    ulonglong2 bReg1 = *(const ulonglong2*)(Bpt + 8);
    f32x4 acc[2];
#pragma unroll
    for (int t = 0; t < 2; ++t)
#pragma unroll
        for (int r = 0; r < 4; ++r) acc[t][r] = 0.0f;
    for (int ks = 0; ks < Kc; ks += 32) {
        *(unsigned*)&As[aru][acu] = aReg;
        *(ulonglong2*)&Bs[br][bc] = bReg0;
        *(ulonglong2*)&Bs[br][bc + 8] = bReg1;
        __syncthreads();
        if (ks + 32 < Kc) {
            aReg = *(const unsigned*)(Apt + ks + 32);
            bReg0 = *(const ulonglong2*)(Bpt + ks + 32);
            bReg1 = *(const ulonglong2*)(Bpt + ks + 32 + 8);
        }
        short8 a = *(const short8*)&As[m][q * 8];
#pragma unroll
        for (int nt = 0; nt < 2; ++nt) {
            short8 bb = *(const short8*)&Bs[w * 32 + nt * 16 + m][q * 8];
            acc[nt] = __builtin_amdgcn_mfma_f32_16x16x32_bf16(a, bb, acc[nt], 0, 0, 0);
        }
        __syncthreads();
    }
    // epilogue: add + bias + d*Y, row l2norm across the 128 cols
    float pre[2][4];
    float ssr[4] = {0.0f, 0.0f, 0.0f, 0.0f};
#pragma unroll
    for (int nt = 0; nt < 2; ++nt) {
        const int col = w * 32 + nt * 16 + m;
        const float bv = bias[col];
#pragma unroll
        for (int r = 0; r < 4; ++r) {
            const int il = q * 4 + r;
            const size_t srow = (size_t)bx * Kc + i0 + il;
            const float v = bv + addP[srow * 128 + col] + sd[il] * acc[nt][r];
            pre[nt][r] = v;
            ssr[r] += v * v;
        }
    }
#pragma unroll
    for (int r = 0; r < 4; ++r) {
        float v = ssr[r];
        v += __shfl_xor(v, 1); v += __shfl_xor(v, 2);
        v += __shfl_xor(v, 4); v += __shfl_xor(v, 8);
        ssr[r] = v;
    }
    if (m == 0) {
#pragma unroll
        for (int r = 0; r < 4; ++r) redA[w][q * 4 + r] = ssr[r];
    }
    __syncthreads();
    float nf[4];
#pragma unroll
    for (int r = 0; r < 4; ++r) {
        const int il = q * 4 + r;
        nf[r] = rsqrtf(redA[0][il] + redA[1][il] + redA[2][il] + redA[3][il]);
    }
    const bool doSc = (scores != nullptr) && (bx == 0);
    float scp[4] = {0.0f, 0.0f, 0.0f, 0.0f};
#pragma unroll
    for (int nt = 0; nt < 2; ++nt) {
        const int col = w * 32 + nt * 16 + m;
        const float wv = doSc ? Wp[col] : 0.0f;
#pragma unroll
        for (int r = 0; r < 4; ++r) {
            const int il = q * 4 + r;
            const size_t srow = (size_t)bx * Kc + i0 + il;
            const float o = pre[nt][r] * nf[r];
            if (f32out) f32out[srow * 128 + col] = o;
            bf16out[srow * 128 + col] = f2bf(o);
            scp[r] = fmaf(o, wv, scp[r]);
        }
    }
    if (doSc) {
#pragma unroll
        for (int r = 0; r < 4; ++r) {
            float v = scp[r];
            v += __shfl_xor(v, 1); v += __shfl_xor(v, 2);
            v += __shfl_xor(v, 4); v += __shfl_xor(v, 8);
            scp[r] = v;
        }
        if (m == 0) {
#pragma unroll
            for (int r = 0; r < 4; ++r) redB[w][q * 4 + r] = scp[r];
        }
        __syncthreads();
        if (tid < 16) {
            const float s = redB[0][tid] + redB[1][tid] + redB[2][tid] + redB[3][tid]
                          + bp[0];
            scores[i0 + tid] = 1.0f / (1.0f + expf(-s));
        }
    }
}

// ---------------- fused gram + NCE sums (+ topk rider / + tail finalize) ---
__launch_bounds__(256)
__global__ void k_nce_topk(const unsigned short* __restrict__ A,
                           const unsigned short* __restrict__ B,
                           float* __restrict__ rowsum, float* __restrict__ colsum,
                           float* __restrict__ pos, int gramBlocks, int bw,
                           const float* __restrict__ scores,
                           float* __restrict__ vals, int* __restrict__ idx,
                           int* __restrict__ counter, float* __restrict__ outT,
                           float invN, int nRows)
{
    __shared__ unsigned short As[64][40];
    __shared__ unsigned short Bs[128][40];
    __shared__ float colbuf[4][128];
    __shared__ unsigned sv[2048];
    __shared__ int hist[256];
    __shared__ int shp, shr, sh_base, sh_out, wsum[5];
    __shared__ int lastFlag;
    const int tid = threadIdx.x;
    const int b = blockIdx.x;
    if (b < gramBlocks) {
        const int bx = b % bw, by = b / bw;
        const int i0 = by * 64;
        const int j0 = bx * 128;
        const int w = tid >> 6;
        const int lane = tid & 63;
        const int m = lane & 15;
        const int q = lane >> 4;
        f32x4 acc[8];
#pragma unroll
        for (int t = 0; t < 8; ++t)
#pragma unroll
            for (int r = 0; r < 4; ++r) acc[t][r] = 0.0f;
        mm64x128(A, 128, B, 128, i0, j0, 0, 128, acc, As, Bs);
        float rpart[4] = {0.0f, 0.0f, 0.0f, 0.0f};
        float cpart[8];
#pragma unroll
        for (int nt = 0; nt < 8; ++nt) {
            const int col = j0 + nt * 16 + m;
            float cs = 0.0f;
#pragma unroll
            for (int r = 0; r < 4; ++r) {
                const int row = i0 + w * 16 + q * 4 + r;
                float g = acc[nt][r];
                float e = __expf(g * TINV);
                if (row == col) { pos[row] = g; e = 0.0f; }
                rpart[r] += e;
                cs += e;
            }
            cpart[nt] = cs;
        }
#pragma unroll
        for (int r = 0; r < 4; ++r) {
            float v = rpart[r];
            v += __shfl_xor(v, 1); v += __shfl_xor(v, 2);
            v += __shfl_xor(v, 4); v += __shfl_xor(v, 8);
            if (m == 0) atomicAdd(&rowsum[i0 + w * 16 + q * 4 + r], v);
        }
#pragma unroll
        for (int nt = 0; nt < 8; ++nt) {
            float v = cpart[nt];
            v += __shfl_xor(v, 16); v += __shfl_xor(v, 32);
            if (q == 0) colbuf[w][nt * 16 + m] = v;
        }
        __syncthreads();
        if (tid < 128) {
            float v = colbuf[0][tid] + colbuf[1][tid] + colbuf[2][tid] + colbuf[3][tid];
            atomicAdd(&colsum[j0 + tid], v);
        }
        // ---- optional tail: last block finalizes the NCE loss -------------
        if (counter) {
            __threadfence();
            __syncthreads();
            if (tid == 0) lastFlag = (atomicAdd(counter, 1) == gramBlocks - 1);
            __syncthreads();
            if (lastFlag) {
                __threadfence();
                float accl = 0.0f;
                for (int i = tid; i < nRows; i += 256) {
                    float p = pos[i] * TINV;
                    float ep = __expf(p);
                    accl += (logf(rowsum[i] + ep) - p) + (logf(colsum[i] + ep) - p);
                }
                float* red = (float*)colbuf;
                red[tid] = accl;
                __syncthreads();
                for (int s = 128; s > 0; s >>= 1) {
                    if (tid < s) red[tid] += red[tid + s];
                    __syncthreads();
                }
                if (tid == 0) atomicAdd(outT, red[0] * invN);
            }
        }
    } else {
        // ---- top-1024-of-2048 radix select, 256 threads ----
        for (int e = tid; e < 2048; e += 256) sv[e] = __float_as_uint(scores[e]);
        if (tid == 0) { shp = 0; shr = 1024; sh_base = 0; sh_out = 0; }
        __syncthreads();
        for (int byte = 3; byte >= 0; --byte) {
            hist[tid] = 0;
            __syncthreads();
            const unsigned pref = (unsigned)shp;
            const unsigned pmask = (byte == 3) ? 0u : (0xFFFFFFFFu << ((byte + 1) * 8));
            for (int e = tid; e < 2048; e += 256) {
                unsigned u = sv[e];
                if ((u & pmask) == (pref & pmask))
                    atomicAdd(&hist[(u >> (byte * 8)) & 255], 1);
            }
            __syncthreads();
            if (tid == 0) {
                int rem = shr, bs = 255;
                for (; bs > 0; --bs) {
                    if (hist[bs] >= rem) break;
                    rem -= hist[bs];
                }
                shp = (int)(pref | ((unsigned)bs << (byte * 8)));
                shr = rem;
            }
            __syncthreads();
        }
        const unsigned t = (unsigned)shp;
        const int remain = shr;
        const int lane = tid & 63, wave = tid >> 6;
        for (int pass = 0; pass < 8; ++pass) {
            const int e = pass * 256 + tid;
            const unsigned u = sv[e];
            const bool eq = (u == t);
            unsigned long long mk = __ballot(eq);
            int wpre = __popcll(mk & ((1ull << lane) - 1ull));
            if (lane == 0) wsum[wave] = __popcll(mk);
            __syncthreads();
            if (tid == 0) {
                int a = sh_base;
                for (int ww = 0; ww < 4; ++ww) { int c = wsum[ww]; wsum[ww] = a; a += c; }
                sh_base = a;
            }
            __syncthreads();
            const int rank = eq ? (wsum[wave] + wpre) : 0x7fffffff;
            if ((u > t) || (eq && rank < remain)) {
                int slot = atomicAdd(&sh_out, 1);
                idx[slot] = e;
                vals[slot] = __uint_as_float(u);
            }
            __syncthreads();
        }
    }
}

// ---------------- NCE finalize (unpooled) + build_ap (32x32 tiles) ---------
__global__ void k_final_ap(const float* __restrict__ rs, const float* __restrict__ cs,
                           const float* __restrict__ pos, float* __restrict__ out,
                           const unsigned long long* __restrict__ bits,
                           const int* __restrict__ idx,
                           unsigned short* __restrict__ Ap, int* __restrict__ degp)
{
    __shared__ unsigned long long pb[32][33];
    __shared__ unsigned long long qb[32][33];
    __shared__ float red[256];
    const int b = blockIdx.x;
    const int tid = threadIdx.x;
    if (b < 1024) {
        const int tp = (b >> 5) * 32;
        const int tq = (b & 31) * 32;
        for (int t = tid; t < 1024; t += 256) {
            int r = t >> 5, w = t & 31;
            pb[r][w] = bits[(size_t)idx[tp + r] * 32 + w];
            qb[r][w] = bits[(size_t)idx[tq + r] * 32 + w];
        }
        __syncthreads();
        const int pi = tid >> 3;            // 0..31
        const int qc0 = (tid & 7) * 4;      // 0,4,..,28
        unsigned long long a0 = 0, a1 = 0, a2 = 0, a3 = 0;
#pragma unroll
        for (int w = 0; w < 32; ++w) {
            const unsigned long long p = pb[pi][w];
            a0 |= p & qb[qc0 + 0][w];
            a1 |= p & qb[qc0 + 1][w];
            a2 |= p & qb[qc0 + 2][w];
            a3 |= p & qb[qc0 + 3][w];
        }
        unsigned short o[4] = { (unsigned short)(a0 ? 0x3F80 : 0),
                                (unsigned short)(a1 ? 0x3F80 : 0),
                                (unsigned short)(a2 ? 0x3F80 : 0),
                                (unsigned short)(a3 ? 0x3F80 : 0) };
        *(ulonglong1*)&Ap[(size_t)(tp + pi) * 1024 + tq + qc0] = *(ulonglong1*)o;
        int v = (a0 ? 1 : 0) + (a1 ? 1 : 0) + (a2 ? 1 : 0) + (a3 ? 1 : 0);
        v += __shfl_xor(v, 1); v += __shfl_xor(v, 2); v += __shfl_xor(v, 4);
        if ((tid & 7) == 0) atomicAdd(&degp[tp + pi], v);
    } else {
        const int i = (b - 1024) * 256 + tid;
        float p = pos[i] * TINV;
        float ep = __expf(p);
        float t = (logf(rs[i] + ep) - p) + (logf(cs[i] + ep) - p);
        red[tid] = t;
        __syncthreads();
        for (int s = 128; s > 0; s >>= 1) {
            if (tid < s) red[tid] += red[tid + s];
            __syncthreads();
        }
        if (tid == 0) atomicAdd(out, red[0] * (1.0f / 2048.0f));
    }
}

// ---- pooled linears with inline gather: z0 -> P0; z1 -> Xtp^T * dinvp -----
__launch_bounds__(256)
__global__ void k_lin_pool(const float* __restrict__ f_g, const int* __restrict__ idx,
                           const float* __restrict__ vals, const int* __restrict__ degp,
                           const unsigned short* __restrict__ WtP,
                           float* __restrict__ P0, unsigned short* __restrict__ Xtp)
{
    __shared__ unsigned short As[64][40];
    __shared__ unsigned short Bs[128][40];
    const int b = blockIdx.x;                    // 64 = 2z x 32 tiles
    const int z = b >> 5;
    const int i0 = (b & 31) * 64;
    const int tid = threadIdx.x;
    const int w = tid >> 6, lane = tid & 63, m = lane & 15, q = lane >> 4;
    const int ar = tid >> 2, ac = (tid & 3) * 8;
    const int hrow = i0 + ar;
    const int p = hrow & 1023;
    const int s = idx[p];
    const float v = vals[p];
    const size_t srow = (size_t)((hrow >= 1024) ? 2048 : 0) + s;
    const int br = tid >> 1, bc = (tid & 1) * 16;
    f32x4 acc[8];
#pragma unroll
    for (int t = 0; t < 8; ++t)
#pragma unroll
        for (int r = 0; r < 4; ++r) acc[t][r] = 0.0f;
    for (int ks = 0; ks < 128; ks += 32) {
        float4 f1 = *(const float4*)(f_g + srow * 128 + ks + ac);
        float4 f2 = *(const float4*)(f_g + srow * 128 + ks + ac + 4);
        short8 pk;
        pk[0] = (short)f2bf(f1.x * v); pk[1] = (short)f2bf(f1.y * v);
        pk[2] = (short)f2bf(f1.z * v); pk[3] = (short)f2bf(f1.w * v);
        pk[4] = (short)f2bf(f2.x * v); pk[5] = (short)f2bf(f2.y * v);
        pk[6] = (short)f2bf(f2.z * v); pk[7] = (short)f2bf(f2.w * v);
        *(short8*)&As[ar][ac] = pk;
        *(ulonglong2*)&Bs[br][bc] =
            *(const ulonglong2*)(WtP + (size_t)z * 16384 + (size_t)br * 128 + ks + bc);
        *(ulonglong2*)&Bs[br][bc + 8] =
            *(const ulonglong2*)(WtP + (size_t)z * 16384 + (size_t)br * 128 + ks + bc + 8);
        __syncthreads();
        short8 a = *(const short8*)&As[w * 16 + m][q * 8];
#pragma unroll
        for (int nt = 0; nt < 8; ++nt) {
            short8 bb = *(const short8*)&Bs[nt * 16 + m][q * 8];
            acc[nt] = __builtin_amdgcn_mfma_f32_16x16x32_bf16(a, bb, acc[nt], 0, 0, 0);
        }
        __syncthreads();
    }
    if (z == 0) {
#pragma unroll
        for (int nt = 0; nt < 8; ++nt) {
            const int col = nt * 16 + m;
#pragma unroll
            for (int r = 0; r < 4; ++r) {
                const int row = i0 + w * 16 + q * 4 + r;
                P0[(size_t)row * 128 + col] = acc[nt][r];
            }
        }
    } else {
        const int boff = (i0 >= 1024) ? 128 : 0;
        const int p0 = (i0 & 1023) + w * 16 + q * 4;
        int4 dg = *(const int4*)(degp + p0);
        const float dvr[4] = { rsqrtf((float)dg.x), rsqrtf((float)dg.y),
                               rsqrtf((float)dg.z), rsqrtf((float)dg.w) };
#pragma unroll
        for (int nt = 0; nt < 8; ++nt) {
            const int n = boff + nt * 16 + m;
            unsigned short o[4];
#pragma unroll
            for (int r = 0; r < 4; ++r) o[r] = f2bf(acc[nt][r] * dvr[r]);
            *(ulonglong1*)&Xtp[(size_t)n * 1024 + p0] = *(ulonglong1*)o;
        }
    }
}

// ---------------------------------------------------------------------------
extern "C" void kernel_launch(void* const* d_in, const int* in_sizes, int n_in,
                              void* d_out, int out_size, void* d_ws, size_t ws_size,
                              hipStream_t stream)
{
    (void)in_sizes; (void)n_in; (void)out_size; (void)ws_size;
    const float* fs      = (const float*)d_in[0];
    const float* ft      = (const float*)d_in[1];
    const float* W_embed = (const float*)d_in[2];
    const float* b_embed = (const float*)d_in[3];
    const float* W_gnn   = (const float*)d_in[4];
    const float* b_gnn   = (const float*)d_in[5];
    const float* W_pool  = (const float*)d_in[6];
    const float* b_pool  = (const float*)d_in[7];
    const float* W_gnnp  = (const float*)d_in[8];
    const float* b_gnnp  = (const float*)d_in[9];
    float* out = (float*)d_out;

    float* ws = (float*)d_ws;
    size_t o = 0;
    auto alloc = [&](size_t n) { float* p = ws + o; o += (n + 3) & ~3ull; return p; };
    float* bigB   = alloc(2048ull * 2048);
    float* f_e    = alloc(4096 * 128);
    float* f_g    = alloc(4096 * 128);
    unsigned short* A01  = (unsigned short*)alloc(2048ull * 2048 / 2);
    unsigned short* feb  = (unsigned short*)alloc(4096ull * 128 / 2);
    unsigned short* Xt1  = (unsigned short*)alloc(256ull * 2048 / 2);
    unsigned short* Xt2  = (unsigned short*)alloc(256ull * 2048 / 2);
    unsigned short* f_gb = (unsigned short*)alloc(4096ull * 128 / 2);
    unsigned short* Wtall= (unsigned short*)alloc(5ull * 16384 / 2);
    unsigned short* Ap01 = (unsigned short*)alloc(1024ull * 1024 / 2);
    unsigned short* Xtp  = (unsigned short*)alloc(256ull * 1024 / 2);
    unsigned short* f_pb = (unsigned short*)alloc(2048ull * 128 / 2);
    float* hW     = alloc(3ull * 4096 * 128);     // hW0 / hW1 / hW2
    float* P0     = alloc(2048ull * 128);         // new_h @ Wp0
    float* dinv   = alloc(2048);
    float* scores = alloc(2048);
    float* vals   = alloc(1024);
    int*   idxb   = (int*)alloc(1024);
    unsigned long long* bits = (unsigned long long*)alloc(2048 * 32 * 2);
    float* nceb = alloc(9216);
    int*   deg  = (int*)alloc(2048);
    int*   degp = (int*)alloc(1024);
    int*   cnt  = (int*)alloc(4);
    const int kZeroCount = 9216 + 2048 + 1024 + 4;   // 12292 (nceb..cnt contiguous)

    const size_t FSTR = 4096ull * 128;
    unsigned short* Wt  = Wtall;
    unsigned short* WtP = Wtall + 3ull * 16384;
    float* hW0 = hW;
    float* hW1 = hW + FSTR;
    float* hW2 = hW + 2 * FSTR;
    float* rs  = nceb;
    float* csu = nceb + 2048;
    float* pos = nceb + 4096;
    float* rsp  = nceb + 6144;
    float* csp  = nceb + 7168;
    float* posp = nceb + 8192;

    // 1. embed GEMM + zero control words + convert weights
    k_setup_embed<<<601, 256, 0, stream>>>(fs, ft, W_embed, bigB, FSTR,
                                           (int*)nceb, kZeroCount, out, W_gnn, W_gnnp, Wtall);
    // 2. embed combine + l2norm -> f_e (fp32), feb (bf16)
    combine_norm<<<4096, 128, 0, stream>>>(bigB, 4, FSTR, b_embed, f_e, feb);
    // 3. fused adjacency gram + threshold + pack + deg, rider: hW{0,1,2}=feb@Wz
    k_gram_fused<<<720, 256, 0, stream>>>(f_e, A01, bits, deg, feb, Wt, hW);
    // 4. Xt1 = (hW2)^T * dinv  (+ dinv)
    make_xt<<<512, 256, 0, stream>>>(hW2, deg, Xt1, dinv);
    // 5. hop1 full-K fused: Xt2 = ((hW1 + dinv*(A01@Xt1)) * dinv)^T
    k_hop_xt2<<<dim3(2, 128), 256, 0, stream>>>(A01, Xt1, dinv, hW1, Xt2);
    // 6. hop2 full-K fused: f_g = l2norm(hW0 + b_gnn + dinv*(A01@Xt2)) + scores
    k_hop_norm<<<dim3(2, 128), 256, 0, stream>>>(A01, 2048, Xt2, hW0, b_gnn,
                                                 dinv, nullptr, f_g, f_gb,
                                                 W_pool, b_pool, scores);
    // 7. graph NCE gram + topk rider
    k_nce_topk<<<513, 256, 0, stream>>>(f_gb, f_gb + 2048 * 128, rs, csu, pos,
                                        512, 16, scores, vals, idxb,
                                        nullptr, nullptr, 0.0f, 0);
    // 8. graph NCE finalize + pooled adjacency (32x32 tiles)
    k_final_ap<<<1032, 256, 0, stream>>>(rs, csu, pos, out, bits, idxb, Ap01, degp);
    // 9. pooled linears w/ inline gather: P0 = new_h@Wp0; Xtp = (new_h@Wp1)^T*dinvp
    k_lin_pool<<<64, 256, 0, stream>>>(f_g, idxb, vals, degp, WtP, P0, Xtp);
    // 10. pooled hop full-K fused: f_p = l2norm(P0 + b_gnnp + dinvp*(Ap01@Xtp))
    k_hop_norm<<<dim3(2, 64), 256, 0, stream>>>(Ap01, 1024, Xtp, P0, b_gnnp,
                                                nullptr, degp, nullptr, f_pb,
                                                nullptr, nullptr, nullptr);
    // 11. pooled NCE gram + tail-block finalize
    k_nce_topk<<<128, 256, 0, stream>>>(f_pb, f_pb + 1024 * 128, rsp, csp, posp,
                                        128, 8, nullptr, nullptr, nullptr,
                                        cnt, out, 1.0f / 1024.0f, 1024);
}

// Round 4
// 200.248 us; speedup vs baseline: 1.1624x; 1.1624x over previous
//
#include <hip/hip_runtime.h>

// ---------------------------------------------------------------------------
// GNNLoss. N=2048, C=512, D=128, K_POOL=1024, T=0.07, NEG=-10.
// Round 18: rebase on R15 16-dispatch structure (208.3us, best); replace the
// two fp32 vector-ALU GEMM cores with compensated hi/lo bf16 MFMA
// (x ~= hi+lo; A.B ~= Ah.Bh + Ah.Bl + Al.Bh, fp32 accum; err ~1e-6):
//   * k_setup_embed GEMM branch: 64x128 MFMA tiles, split-K4 (256 blocks),
//     fs/ft split in-register during A-staging, W transposed+split in B-staging.
//   * k_gram_fused gram branch: 64x64 MFMA tiles over feb_hi/feb_lo, new
//     byte-predicate epilogue -> same chk/chkT 64-bit masks as before.
//   * combine_norm emits feb_hi + feb_lo (fp32 f_e output dead).
// R17 lesson: boundary cost ~2us (not 7-8); exec time dominates -> attack the
// fp32 cores. R17's skinny full-K hop tiles reverted (barrier-bound).
// Rules: no cross-WG sync; hop/tag GEMMs keep 64x128 split-K shape (R12).
// ---------------------------------------------------------------------------

#define TINV (1.0f / 0.07f)

using short8 = __attribute__((ext_vector_type(8))) short;
using f32x4  = __attribute__((ext_vector_type(4))) float;

__device__ __forceinline__ unsigned short f2bf(float f) {
    unsigned u = __float_as_uint(f);
    u += 0x7fff + ((u >> 16) & 1);
    return (unsigned short)(u >> 16);
}
__device__ __forceinline__ float bf2f(unsigned short h) {
    return __uint_as_float((unsigned)h << 16);
}
__device__ __forceinline__ void splitbf(float f, unsigned short& h, unsigned short& l) {
    h = f2bf(f);
    l = f2bf(f - bf2f(h));
}

// ---------------- bf16 MFMA 64x128 tile core (gram/NCE kernels) ------------
__device__ __forceinline__ void mm64x128(const unsigned short* __restrict__ Ab, int lda,
                                         const unsigned short* __restrict__ Bb, int ldb,
                                         int i0, int j0, int k0, int Kc,
                                         f32x4 (&acc)[8],
                                         unsigned short (&As)[64][40],
                                         unsigned short (&Bs)[128][40])
{
    const int tid = threadIdx.x;
    const int w = tid >> 6;
    const int lane = tid & 63;
    const int m = lane & 15;
    const int q = lane >> 4;
    const int ar = tid >> 2;
    const int ac = (tid & 3) * 8;
    for (int ks = 0; ks < Kc; ks += 32) {
        const int k = k0 + ks;
        *(ulonglong2*)&As[ar][ac] =
            *(const ulonglong2*)(Ab + (size_t)(i0 + ar) * lda + k + ac);
        *(ulonglong2*)&Bs[ar][ac] =
            *(const ulonglong2*)(Bb + (size_t)(j0 + ar) * ldb + k + ac);
        *(ulonglong2*)&Bs[ar + 64][ac] =
            *(const ulonglong2*)(Bb + (size_t)(j0 + ar + 64) * ldb + k + ac);
        __syncthreads();
        short8 a = *(const short8*)&As[w * 16 + m][q * 8];
#pragma unroll
        for (int nt = 0; nt < 8; ++nt) {
            short8 b = *(const short8*)&Bs[nt * 16 + m][q * 8];
            acc[nt] = __builtin_amdgcn_mfma_f32_16x16x32_bf16(a, b, acc[nt], 0, 0, 0);
        }
        __syncthreads();
    }
}

// ------ launch 1: embed GEMM (hi/lo bf16 MFMA, split-K4) + setup roles -----
__launch_bounds__(256)
__global__ void k_setup_embed(const float* __restrict__ fs, const float* __restrict__ ft,
                              const float* __restrict__ W, float* __restrict__ part,
                              size_t zstr, int* __restrict__ zwords, int zcount,
                              float* __restrict__ out,
                              const float* __restrict__ Wg, const float* __restrict__ Wp,
                              unsigned short* __restrict__ Wtall)
{
    __shared__ unsigned short Ah[64][40];
    __shared__ unsigned short Al[64][40];
    __shared__ unsigned short Bh[128][40];
    __shared__ unsigned short Bl[128][40];
    const int b = blockIdx.x;
    const int tid = threadIdx.x;
    if (b < 256) {
        // out[row][col] = sum_k A[row][k] * W[k][col], K-chunk z*128..+128
        const int z = b & 3;
        const int my = b >> 2;                   // 0..63 (row-tile)
        const float* A = (my < 32) ? ft : fs;
        const int i0 = (my & 31) * 64;
        const int w = tid >> 6, lane = tid & 63, m = lane & 15, q = lane >> 4;
        const int ar = tid >> 2, ac = (tid & 3) * 8;
        const int wkk = tid >> 3, wc0 = (tid & 7) * 16;
        f32x4 acc[8];
#pragma unroll
        for (int t = 0; t < 8; ++t)
#pragma unroll
            for (int r = 0; r < 4; ++r) acc[t][r] = 0.0f;
        for (int ks = 0; ks < 128; ks += 32) {
            const int k = z * 128 + ks;
            // A-tile: 64 rows x 32 k, fp32 -> hi/lo
            {
                float4 f1 = *(const float4*)(A + (size_t)(i0 + ar) * 512 + k + ac);
                float4 f2 = *(const float4*)(A + (size_t)(i0 + ar) * 512 + k + ac + 4);
                unsigned short h[8], l[8];
                splitbf(f1.x, h[0], l[0]); splitbf(f1.y, h[1], l[1]);
                splitbf(f1.z, h[2], l[2]); splitbf(f1.w, h[3], l[3]);
                splitbf(f2.x, h[4], l[4]); splitbf(f2.y, h[5], l[5]);
                splitbf(f2.z, h[6], l[6]); splitbf(f2.w, h[7], l[7]);
#pragma unroll
                for (int j = 0; j < 8; ++j) { Ah[ar][ac + j] = h[j]; Al[ar][ac + j] = l[j]; }
            }
            // B-tile: Bs[col][kk] = W[k+kk][col], 32 kk x 128 cols, transpose+split
            {
                const float* Wr = W + (size_t)(k + wkk) * 128 + wc0;
#pragma unroll
                for (int jj = 0; jj < 4; ++jj) {
                    float4 f = *(const float4*)(Wr + jj * 4);
                    unsigned short h, l;
                    splitbf(f.x, h, l); Bh[wc0 + jj*4 + 0][wkk] = h; Bl[wc0 + jj*4 + 0][wkk] = l;
                    splitbf(f.y, h, l); Bh[wc0 + jj*4 + 1][wkk] = h; Bl[wc0 + jj*4 + 1][wkk] = l;
                    splitbf(f.z, h, l); Bh[wc0 + jj*4 + 2][wkk] = h; Bl[wc0 + jj*4 + 2][wkk] = l;
                    splitbf(f.w, h, l); Bh[wc0 + jj*4 + 3][wkk] = h; Bl[wc0 + jj*4 + 3][wkk] = l;
                }
            }
            __syncthreads();
            short8 ah = *(const short8*)&Ah[w * 16 + m][q * 8];
            short8 al = *(const short8*)&Al[w * 16 + m][q * 8];
#pragma unroll
            for (int nt = 0; nt < 8; ++nt) {
                short8 bh = *(const short8*)&Bh[nt * 16 + m][q * 8];
                short8 bl = *(const short8*)&Bl[nt * 16 + m][q * 8];
                acc[nt] = __builtin_amdgcn_mfma_f32_16x16x32_bf16(ah, bh, acc[nt], 0, 0, 0);
                acc[nt] = __builtin_amdgcn_mfma_f32_16x16x32_bf16(ah, bl, acc[nt], 0, 0, 0);
                acc[nt] = __builtin_amdgcn_mfma_f32_16x16x32_bf16(al, bh, acc[nt], 0, 0, 0);
            }
            __syncthreads();
        }
        float* dst = part + (size_t)z * zstr;
#pragma unroll
        for (int nt = 0; nt < 8; ++nt) {
            const int col = nt * 16 + m;
#pragma unroll
            for (int r = 0; r < 4; ++r) {
                const int row = my * 64 + w * 16 + q * 4 + r;
                dst[(size_t)row * 128 + col] = acc[nt][r];
            }
        }
    } else if (b < 305) {
        const int i = (b - 256) * 256 + tid;
        if (i < zcount) zwords[i] = 0;
        if (b == 256 && tid == 0) out[0] = 0.0f;
    } else {
        const int e0 = (b - 305) * 2048 + tid;
#pragma unroll
        for (int it = 0; it < 8; ++it) {
            const int e = e0 + it * 256;
            const int c = e >> 14;
            const int rem = e & 16383;
            const int n = rem >> 7, k = rem & 127;
            const float* src = (c < 3) ? (Wg + (size_t)c * 16384)
                                       : (Wp + (size_t)(c - 3) * 16384);
            Wtall[e] = f2bf(src[(size_t)k * 128 + n]);
        }
    }
}

// ------- combine embed partials + bias + l2norm -> feb hi/lo ---------------
__global__ void combine_norm(const float* __restrict__ part, int nz, size_t zstr,
                             const float* __restrict__ bias,
                             unsigned short* __restrict__ bfh,
                             unsigned short* __restrict__ bfl)
{
    const int row = blockIdx.x;
    const int tid = threadIdx.x;                 // 128
    float v = bias[tid];
    for (int z = 0; z < nz; ++z) v += part[(size_t)z * zstr + (size_t)row * 128 + tid];
    __shared__ float red[128];
    red[tid] = v * v;
    __syncthreads();
    for (int s = 64; s > 0; s >>= 1) {
        if (tid < s) red[tid] += red[tid + s];
        __syncthreads();
    }
    const float o = v * (1.0f / sqrtf(red[0]));
    unsigned short h, l;
    splitbf(o, h, l);
    bfh[(size_t)row * 128 + tid] = h;
    bfl[(size_t)row * 128 + tid] = l;
}

// ---- fused gram (hi/lo MFMA) + threshold + pack + (rider) 3x TAG linears --
__launch_bounds__(256)
__global__ void k_gram_fused(const unsigned short* __restrict__ febh,
                             const unsigned short* __restrict__ febl,
                             unsigned short* __restrict__ A01,
                             unsigned long long* __restrict__ bits,
                             int* __restrict__ deg,
                             const unsigned short* __restrict__ Wt,
                             float* __restrict__ hW)
{
    __shared__ __align__(16) unsigned char smem[25600];
    const int b = blockIdx.x;
    const int tid = threadIdx.x;
    if (b >= 528) {
        // rider: hW[z] = feb_hi @ Wt[z]^T  (M=4096, N=128, K=128)
        unsigned short (&As2)[64][40]  = *reinterpret_cast<unsigned short(*)[64][40]>(smem);
        unsigned short (&Bs2)[128][40] = *reinterpret_cast<unsigned short(*)[128][40]>(smem + 5120);
        const int lb = b - 528;
        const int z = lb >> 6;
        const int i0 = (lb & 63) * 64;
        f32x4 acc[8];
#pragma unroll
        for (int t = 0; t < 8; ++t)
#pragma unroll
            for (int r = 0; r < 4; ++r) acc[t][r] = 0.0f;
        mm64x128(febh, 128, Wt + (size_t)z * 16384, 128, i0, 0, 0, 128, acc, As2, Bs2);
        const int w = tid >> 6, lane = tid & 63, m = lane & 15, q = lane >> 4;
        float* Cb = hW + (size_t)z * (4096ull * 128);
#pragma unroll
        for (int nt = 0; nt < 8; ++nt) {
            const int col = nt * 16 + m;
#pragma unroll
            for (int r = 0; r < 4; ++r) {
                const int row = i0 + w * 16 + q * 4 + r;
                Cb[(size_t)row * 128 + col] = acc[nt][r];
            }
        }
        return;
    }
    // ---- gram branch: 64x64 tile, C = fe @ fe^T over teacher rows ----------
    unsigned short (&Ah)[64][40] = *reinterpret_cast<unsigned short(*)[64][40]>(smem);
    unsigned short (&Al)[64][40] = *reinterpret_cast<unsigned short(*)[64][40]>(smem + 5120);
    unsigned short (&Bh)[64][40] = *reinterpret_cast<unsigned short(*)[64][40]>(smem + 10240);
    unsigned short (&Bl)[64][40] = *reinterpret_cast<unsigned short(*)[64][40]>(smem + 15360);
    unsigned char (&predB)[64][64] = *reinterpret_cast<unsigned char(*)[64][64]>(smem + 20480);
    unsigned long long (&chk)[64]  = *reinterpret_cast<unsigned long long(*)[64]>(smem + 24576);
    unsigned long long (&chkT)[64] = *reinterpret_cast<unsigned long long(*)[64]>(smem + 25088);
    int by = (int)((sqrtf(8.0f * b + 1.0f) - 1.0f) * 0.5f);
    while ((by + 1) * (by + 2) / 2 <= b) ++by;
    while (by * (by + 1) / 2 > b) --by;
    const int bx = b - by * (by + 1) / 2;
    const int i0 = by * 64, j0 = bx * 64;
    const int w = tid >> 6, lane = tid & 63, m = lane & 15, q = lane >> 4;
    const int ar = tid >> 2, ac = (tid & 3) * 8;
    f32x4 acc[4];
#pragma unroll
    for (int t = 0; t < 4; ++t)
#pragma unroll
        for (int r = 0; r < 4; ++r) acc[t][r] = 0.0f;
    for (int ks = 0; ks < 128; ks += 32) {
        *(ulonglong2*)&Ah[ar][ac] = *(const ulonglong2*)(febh + (size_t)(i0 + ar) * 128 + ks + ac);
        *(ulonglong2*)&Al[ar][ac] = *(const ulonglong2*)(febl + (size_t)(i0 + ar) * 128 + ks + ac);
        *(ulonglong2*)&Bh[ar][ac] = *(const ulonglong2*)(febh + (size_t)(j0 + ar) * 128 + ks + ac);
        *(ulonglong2*)&Bl[ar][ac] = *(const ulonglong2*)(febl + (size_t)(j0 + ar) * 128 + ks + ac);
        __syncthreads();
        short8 ah = *(const short8*)&Ah[w * 16 + m][q * 8];
        short8 al = *(const short8*)&Al[w * 16 + m][q * 8];
#pragma unroll
        for (int nt = 0; nt < 4; ++nt) {
            short8 bh = *(const short8*)&Bh[nt * 16 + m][q * 8];
            short8 bl = *(const short8*)&Bl[nt * 16 + m][q * 8];
            acc[nt] = __builtin_amdgcn_mfma_f32_16x16x32_bf16(ah, bh, acc[nt], 0, 0, 0);
            acc[nt] = __builtin_amdgcn_mfma_f32_16x16x32_bf16(ah, bl, acc[nt], 0, 0, 0);
            acc[nt] = __builtin_amdgcn_mfma_f32_16x16x32_bf16(al, bh, acc[nt], 0, 0, 0);
        }
        __syncthreads();
    }
    // predicate bytes: predB[localRow][localCol]
#pragma unroll
    for (int nt = 0; nt < 4; ++nt) {
        const int lc = nt * 16 + m;
#pragma unroll
        for (int r = 0; r < 4; ++r) {
            const int lr = w * 16 + q * 4 + r;
            bool pred = (acc[nt][r] > 0.0f) || (i0 + lr == j0 + lc);
            predB[lr][lc] = pred ? 1 : 0;
        }
    }
    __syncthreads();
    if (tid < 64) {
        unsigned long long c = 0;
        const unsigned* rowp = (const unsigned*)predB[tid];
#pragma unroll
        for (int t = 0; t < 16; ++t) {
            unsigned u = rowp[t];
            c |= (unsigned long long)((u >> 0) & 1) << (4 * t + 0);
            c |= (unsigned long long)((u >> 8) & 1) << (4 * t + 1);
            c |= (unsigned long long)((u >> 16) & 1) << (4 * t + 2);
            c |= (unsigned long long)((u >> 24) & 1) << (4 * t + 3);
        }
        chk[tid] = c;
        bits[(size_t)(i0 + tid) * 32 + (j0 >> 6)] = c;
        atomicAdd(&deg[i0 + tid], __popcll(c));
    } else if (tid < 128 && bx != by) {
        const int r = tid - 64;
        unsigned long long c = 0;
#pragma unroll
        for (int i = 0; i < 64; ++i)
            c |= (unsigned long long)(predB[i][r] & 1) << i;
        chkT[r] = c;
        bits[(size_t)(j0 + r) * 32 + (i0 >> 6)] = c;
        atomicAdd(&deg[j0 + r], __popcll(c));
    }
    __syncthreads();
    // packed 8B stores: 4 iters x (16 rows x 16 col-groups of 4)
#pragma unroll
    for (int it = 0; it < 4; ++it) {
        const int row = it * 16 + (tid >> 4);
        const int c0 = (tid & 15) * 4;
        unsigned short o[4];
#pragma unroll
        for (int c = 0; c < 4; ++c)
            o[c] = ((chk[row] >> (c0 + c)) & 1) ? (unsigned short)0x3F80 : (unsigned short)0;
        *(ulonglong1*)&A01[(size_t)(i0 + row) * 2048 + j0 + c0] = *(ulonglong1*)o;
        if (bx != by) {
            unsigned short o2[4];
#pragma unroll
            for (int c = 0; c < 4; ++c)
                o2[c] = ((chkT[row] >> (c0 + c)) & 1) ? (unsigned short)0x3F80 : (unsigned short)0;
            *(ulonglong1*)&A01[(size_t)(j0 + row) * 2048 + i0 + c0] = *(ulonglong1*)o2;
        }
    }
}

// ---------------- universal bf16 MFMA GEMM (plain store) -------------------
__launch_bounds__(256)
__global__ void mm_bf16(const unsigned short* __restrict__ A, int lda, size_t aZ,
                        const unsigned short* __restrict__ B, int ldb, size_t bZ,
                        float* __restrict__ C, int ldc, size_t cZ,
                        int Kc, int kZ)
{
    __shared__ unsigned short As[64][40];
    __shared__ unsigned short Bs[128][40];
    const int tid = threadIdx.x;
    const int bz = blockIdx.z;
    const int i0 = blockIdx.y * 64;
    const int j0 = blockIdx.x * 128;
    const int k0 = bz * kZ;
    const unsigned short* Ab = A + (size_t)bz * aZ;
    const unsigned short* Bb = B + (size_t)bz * bZ;
    float* Cb = C + (size_t)bz * cZ;
    f32x4 acc[8];
#pragma unroll
    for (int t = 0; t < 8; ++t)
#pragma unroll
        for (int r = 0; r < 4; ++r) acc[t][r] = 0.0f;
    mm64x128(Ab, lda, Bb, ldb, i0, j0, k0, Kc, acc, As, Bs);
    const int w = tid >> 6, lane = tid & 63, m = lane & 15, q = lane >> 4;
#pragma unroll
    for (int nt = 0; nt < 8; ++nt) {
        const int col = j0 + nt * 16 + m;
#pragma unroll
        for (int r = 0; r < 4; ++r) {
            const int row = i0 + w * 16 + q * 4 + r;
            Cb[(size_t)row * ldc + col] = acc[nt][r];
        }
    }
}

// ------------- reduce hop1 split-K partials -> Xt2 = (hW1 + d*Y1)*d --------
__global__ void reduce_xt(const float* __restrict__ part, int nz, size_t zstr,
                          int M, const float* __restrict__ dinv,
                          const float* __restrict__ addT,
                          unsigned short* __restrict__ xt)
{
    __shared__ float T[32][33];
    const int tid = threadIdx.x;
    const int iloc = tid >> 3, nq = (tid & 7) * 4;
    const int n = blockIdx.x * 32 + nq;
    const int i = blockIdx.y * 32 + iloc;
    float4 s = *(const float4*)(part + (size_t)i * 256 + n);
    for (int z = 1; z < nz; ++z) {
        float4 t = *(const float4*)(part + (size_t)z * zstr + (size_t)i * 256 + n);
        s.x += t.x; s.y += t.y; s.z += t.z; s.w += t.w;
    }
    const float d = dinv[i];
    const int srow = (n >= 128 ? M : 0) + i;
    float4 a = *(const float4*)(addT + (size_t)srow * 128 + (n & 127));
    T[nq + 0][iloc] = (a.x + s.x * d) * d;
    T[nq + 1][iloc] = (a.y + s.y * d) * d;
    T[nq + 2][iloc] = (a.z + s.z * d) * d;
    T[nq + 3][iloc] = (a.w + s.w * d) * d;
    __syncthreads();
    const int nloc = tid >> 3, ic = (tid & 7) * 4;
    unsigned short o2[4];
#pragma unroll
    for (int c = 0; c < 4; ++c) o2[c] = f2bf(T[nloc][ic + c]);
    *(ulonglong1*)(xt + (size_t)(blockIdx.x * 32 + nloc) * M + blockIdx.y * 32 + ic) =
        *(ulonglong1*)o2;
}

// ------- fused: sum split-K + d*() + add + bias + l2norm (+ scores) --------
__global__ void combine_tag(const float* __restrict__ part, int nz, size_t zstr,
                            int Mnodes,
                            const float* __restrict__ add,
                            const float* __restrict__ dinv,
                            const float* __restrict__ bias,
                            float* __restrict__ f32out,
                            unsigned short* __restrict__ bf16out,
                            const float* __restrict__ Wp, const float* __restrict__ bp,
                            float* __restrict__ scores)
{
    const int row = blockIdx.x;
    const int tid = threadIdx.x;                 // 128
    const int node = (row < Mnodes) ? row : row - Mnodes;
    const int boff = (row < Mnodes) ? 0 : 128;
    float s = 0.0f;
    for (int z = 0; z < nz; ++z)
        s += part[(size_t)z * zstr + (size_t)node * 256 + boff + tid];
    float v = bias[tid] + add[(size_t)row * 128 + tid] + dinv[node] * s;
    __shared__ float red[128];
    red[tid] = v * v;
    __syncthreads();
    for (int st = 64; st > 0; st >>= 1) {
        if (tid < st) red[tid] += red[tid + st];
        __syncthreads();
    }
    const float o = v * (1.0f / sqrtf(red[0]));
    if (f32out) f32out[(size_t)row * 128 + tid] = o;
    bf16out[(size_t)row * 128 + tid] = f2bf(o);
    if (Wp && row < Mnodes) {
        __syncthreads();
        red[tid] = o * Wp[tid];
        __syncthreads();
        for (int st = 64; st > 0; st >>= 1) {
            if (tid < st) red[tid] += red[tid + st];
            __syncthreads();
        }
        if (tid == 0) scores[row] = 1.0f / (1.0f + expf(-(red[0] + bp[0])));
    }
}

// ------------- Xt1[n][i] = hW2[(branch)i][n&127] / sqrt(deg[i]) ------------
__global__ void make_xt(const float* __restrict__ src, const int* __restrict__ deg,
                        unsigned short* __restrict__ xt, float* __restrict__ dinv)
{
    __shared__ float T[32][33];
    const int b = blockIdx.x;                    // 512 = 8 x 64
    const int bx = b & 7, by = b >> 3;
    const int tid = threadIdx.x;                 // 256
    const int iloc = tid >> 3, nq = (tid & 7) * 4;
    const int n0 = bx * 32;
    const int i = by * 32 + iloc;
    const int srow = (n0 >= 128 ? 2048 : 0) + i;
    float4 f = *(const float4*)(src + (size_t)srow * 128 + ((n0 + nq) & 127));
    const float d = 1.0f / sqrtf((float)deg[i]);
    if (bx == 0 && (tid & 7) == 0) dinv[i] = d;
    T[nq + 0][iloc] = f.x * d; T[nq + 1][iloc] = f.y * d;
    T[nq + 2][iloc] = f.z * d; T[nq + 3][iloc] = f.w * d;
    __syncthreads();
    const int nloc = tid >> 3, ic = (tid & 7) * 4;
    unsigned short o[4];
#pragma unroll
    for (int c = 0; c < 4; ++c) o[c] = f2bf(T[nloc][ic + c]);
    *(ulonglong1*)(xt + (size_t)(n0 + nloc) * 2048 + by * 32 + ic) = *(ulonglong1*)o;
}

// ---------------- fused gram + NCE sums (+ optional topk rider block) ------
__launch_bounds__(256)
__global__ void k_nce_topk(const unsigned short* __restrict__ A,
                           const unsigned short* __restrict__ B,
                           float* __restrict__ rowsum, float* __restrict__ colsum,
                           float* __restrict__ pos, int gramBlocks, int bw,
                           const float* __restrict__ scores,
                           float* __restrict__ vals, int* __restrict__ idx)
{
    __shared__ unsigned short As[64][40];
    __shared__ unsigned short Bs[128][40];
    __shared__ float colbuf[4][128];
    __shared__ unsigned sv[2048];
    __shared__ int hist[256];
    __shared__ int shp, shr, sh_base, sh_out, wsum[5];
    const int tid = threadIdx.x;
    const int b = blockIdx.x;
    if (b < gramBlocks) {
        const int bx = b % bw, by = b / bw;
        const int i0 = by * 64;
        const int j0 = bx * 128;
        const int w = tid >> 6;
        const int lane = tid & 63;
        const int m = lane & 15;
        const int q = lane >> 4;
        f32x4 acc[8];
#pragma unroll
        for (int t = 0; t < 8; ++t)
#pragma unroll
            for (int r = 0; r < 4; ++r) acc[t][r] = 0.0f;
        mm64x128(A, 128, B, 128, i0, j0, 0, 128, acc, As, Bs);
        float rpart[4] = {0.0f, 0.0f, 0.0f, 0.0f};
        float cpart[8];
#pragma unroll
        for (int nt = 0; nt < 8; ++nt) {
            const int col = j0 + nt * 16 + m;
            float cs = 0.0f;
#pragma unroll
            for (int r = 0; r < 4; ++r) {
                const int row = i0 + w * 16 + q * 4 + r;
                float g = acc[nt][r];
                float e = __expf(g * TINV);
                if (row == col) { pos[row] = g; e = 0.0f; }
                rpart[r] += e;
                cs += e;
            }
            cpart[nt] = cs;
        }
#pragma unroll
        for (int r = 0; r < 4; ++r) {
            float v = rpart[r];
            v += __shfl_xor(v, 1); v += __shfl_xor(v, 2);
            v += __shfl_xor(v, 4); v += __shfl_xor(v, 8);
            if (m == 0) atomicAdd(&rowsum[i0 + w * 16 + q * 4 + r], v);
        }
#pragma unroll
        for (int nt = 0; nt < 8; ++nt) {
            float v = cpart[nt];
            v += __shfl_xor(v, 16); v += __shfl_xor(v, 32);
            if (q == 0) colbuf[w][nt * 16 + m] = v;
        }
        __syncthreads();
        if (tid < 128) {
            float v = colbuf[0][tid] + colbuf[1][tid] + colbuf[2][tid] + colbuf[3][tid];
            atomicAdd(&colsum[j0 + tid], v);
        }
    } else {
        // ---- top-1024-of-2048 radix select, 256 threads ----
        for (int e = tid; e < 2048; e += 256) sv[e] = __float_as_uint(scores[e]);
        if (tid == 0) { shp = 0; shr = 1024; sh_base = 0; sh_out = 0; }
        __syncthreads();
        for (int byte = 3; byte >= 0; --byte) {
            hist[tid] = 0;
            __syncthreads();
            const unsigned pref = (unsigned)shp;
            const unsigned pmask = (byte == 3) ? 0u : (0xFFFFFFFFu << ((byte + 1) * 8));
            for (int e = tid; e < 2048; e += 256) {
                unsigned u = sv[e];
                if ((u & pmask) == (pref & pmask))
                    atomicAdd(&hist[(u >> (byte * 8)) & 255], 1);
            }
            __syncthreads();
            if (tid == 0) {
                int rem = shr, bs = 255;
                for (; bs > 0; --bs) {
                    if (hist[bs] >= rem) break;
                    rem -= hist[bs];
                }
                shp = (int)(pref | ((unsigned)bs << (byte * 8)));
                shr = rem;
            }
            __syncthreads();
        }
        const unsigned t = (unsigned)shp;
        const int remain = shr;
        const int lane = tid & 63, wave = tid >> 6;
        for (int pass = 0; pass < 8; ++pass) {
            const int e = pass * 256 + tid;
            const unsigned u = sv[e];
            const bool eq = (u == t);
            unsigned long long mk = __ballot(eq);
            int wpre = __popcll(mk & ((1ull << lane) - 1ull));
            if (lane == 0) wsum[wave] = __popcll(mk);
            __syncthreads();
            if (tid == 0) {
                int a = sh_base;
                for (int ww = 0; ww < 4; ++ww) { int c = wsum[ww]; wsum[ww] = a; a += c; }
                sh_base = a;
            }
            __syncthreads();
            const int rank = eq ? (wsum[wave] + wpre) : 0x7fffffff;
            if ((u > t) || (eq && rank < remain)) {
                int slot = atomicAdd(&sh_out, 1);
                idx[slot] = e;
                vals[slot] = __uint_as_float(u);
            }
            __syncthreads();
        }
    }
}

// ---------------- NCE finalize + build_ap (32x32 tiles) --------------------
__global__ void k_final_ap(const float* __restrict__ rs, const float* __restrict__ cs,
                           const float* __restrict__ pos, float* __restrict__ out,
                           const unsigned long long* __restrict__ bits,
                           const int* __restrict__ idx,
                           unsigned short* __restrict__ Ap, int* __restrict__ degp)
{
    __shared__ unsigned long long pb[32][33];
    __shared__ unsigned long long qb[32][33];
    __shared__ float red[256];
    const int b = blockIdx.x;
    const int tid = threadIdx.x;
    if (b < 1024) {
        const int tp = (b >> 5) * 32;
        const int tq = (b & 31) * 32;
        for (int t = tid; t < 1024; t += 256) {
            int r = t >> 5, w = t & 31;
            pb[r][w] = bits[(size_t)idx[tp + r] * 32 + w];
            qb[r][w] = bits[(size_t)idx[tq + r] * 32 + w];
        }
        __syncthreads();
        const int pi = tid >> 3;            // 0..31
        const int qc0 = (tid & 7) * 4;      // 0,4,..,28
        unsigned long long a0 = 0, a1 = 0, a2 = 0, a3 = 0;
#pragma unroll
        for (int w = 0; w < 32; ++w) {
            const unsigned long long p = pb[pi][w];
            a0 |= p & qb[qc0 + 0][w];
            a1 |= p & qb[qc0 + 1][w];
            a2 |= p & qb[qc0 + 2][w];
            a3 |= p & qb[qc0 + 3][w];
        }
        unsigned short o[4] = { (unsigned short)(a0 ? 0x3F80 : 0),
                                (unsigned short)(a1 ? 0x3F80 : 0),
                                (unsigned short)(a2 ? 0x3F80 : 0),
                                (unsigned short)(a3 ? 0x3F80 : 0) };
        *(ulonglong1*)&Ap[(size_t)(tp + pi) * 1024 + tq + qc0] = *(ulonglong1*)o;
        int v = (a0 ? 1 : 0) + (a1 ? 1 : 0) + (a2 ? 1 : 0) + (a3 ? 1 : 0);
        v += __shfl_xor(v, 1); v += __shfl_xor(v, 2); v += __shfl_xor(v, 4);
        if ((tid & 7) == 0) atomicAdd(&degp[tp + pi], v);
    } else {
        const int i = (b - 1024) * 256 + tid;
        float p = pos[i] * TINV;
        float ep = __expf(p);
        float t = (logf(rs[i] + ep) - p) + (logf(cs[i] + ep) - p);
        red[tid] = t;
        __syncthreads();
        for (int s = 128; s > 0; s >>= 1) {
            if (tid < s) red[tid] += red[tid + s];
            __syncthreads();
        }
        if (tid == 0) atomicAdd(out, red[0] * (1.0f / 2048.0f));
    }
}

// ---------------- NCE finalize (pooled) ------------------------------------
__global__ void nce_final(const float* __restrict__ rs, const float* __restrict__ cs,
                          const float* __restrict__ pos, float invN,
                          float* __restrict__ out)
{
    const int i = blockIdx.x * 256 + threadIdx.x;
    float p = pos[i] * TINV;
    float ep = __expf(p);
    float t = (logf(rs[i] + ep) - p) + (logf(cs[i] + ep) - p);
    __shared__ float red[256];
    red[threadIdx.x] = t;
    __syncthreads();
    for (int s = 128; s > 0; s >>= 1) {
        if (threadIdx.x < s) red[threadIdx.x] += red[threadIdx.x + s];
        __syncthreads();
    }
    if (threadIdx.x == 0) atomicAdd(out, red[0] * invN);
}

// ------------- gather pooled features (new_h bf16) + dinvp -----------------
__global__ void gather_nh(const float* __restrict__ f_g, const int* __restrict__ idx,
                          const float* __restrict__ vals, const int* __restrict__ degp,
                          unsigned short* __restrict__ nhb, float* __restrict__ dinvp)
{
    const int b = blockIdx.x;                    // 256
    const int tid = threadIdx.x;                 // 256
    if (b < 4) {
        const int p2 = b * 256 + tid;
        dinvp[p2] = 1.0f / sqrtf((float)degp[p2]);
    }
    const int hrow = b * 8 + (tid >> 5);
    const int cq = (tid & 31) * 4;
    const int p = hrow & 1023;
    const int s = idx[p];
    const float v = vals[p];
    const int srow = (hrow >= 1024 ? 2048 : 0) + s;
    float4 f = *(const float4*)(f_g + (size_t)srow * 128 + cq);
    unsigned short o[4] = { f2bf(f.x * v), f2bf(f.y * v), f2bf(f.z * v), f2bf(f.w * v) };
    *(ulonglong1*)&nhb[(size_t)hrow * 128 + cq] = *(ulonglong1*)o;
}

// ---- pooled linears: z0 -> P0 fp32 plain; z1 -> Xtp transposed*dinvp ------
__launch_bounds__(256)
__global__ void k_lin_pool(const unsigned short* __restrict__ nhb,
                           const unsigned short* __restrict__ WtP,
                           const float* __restrict__ dinvp,
                           float* __restrict__ P0,
                           unsigned short* __restrict__ Xtp)
{
    __shared__ unsigned short As[64][40];
    __shared__ unsigned short Bs[128][40];
    const int b = blockIdx.x;                    // 64 = 2z x 32 tiles
    const int z = b >> 5;
    const int i0 = (b & 31) * 64;
    const int tid = threadIdx.x;
    f32x4 acc[8];
#pragma unroll
    for (int t = 0; t < 8; ++t)
#pragma unroll
        for (int r = 0; r < 4; ++r) acc[t][r] = 0.0f;
    mm64x128(nhb, 128, WtP + (size_t)z * 16384, 128, i0, 0, 0, 128, acc, As, Bs);
    const int w = tid >> 6, lane = tid & 63, m = lane & 15, q = lane >> 4;
    if (z == 0) {
#pragma unroll
        for (int nt = 0; nt < 8; ++nt) {
            const int col = nt * 16 + m;
#pragma unroll
            for (int r = 0; r < 4; ++r) {
                const int row = i0 + w * 16 + q * 4 + r;
                P0[(size_t)row * 128 + col] = acc[nt][r];
            }
        }
    } else {
        // acc[nt][r] = P1[i0 + w*16 + q*4 + r][nt*16 + m]; 4 r's are 4
        // consecutive pool indices -> packed 8B transposed stores.
        const int boff = (i0 >= 1024) ? 128 : 0;
        const int p0 = (i0 & 1023) + w * 16 + q * 4;
        float4 dv = *(const float4*)(dinvp + p0);
        const float dvr[4] = { dv.x, dv.y, dv.z, dv.w };
#pragma unroll
        for (int nt = 0; nt < 8; ++nt) {
            const int n = boff + nt * 16 + m;
            unsigned short o[4];
#pragma unroll
            for (int r = 0; r < 4; ++r) o[r] = f2bf(acc[nt][r] * dvr[r]);
            *(ulonglong1*)&Xtp[(size_t)n * 1024 + p0] = *(ulonglong1*)o;
        }
    }
}

// ---------------------------------------------------------------------------
extern "C" void kernel_launch(void* const* d_in, const int* in_sizes, int n_in,
                              void* d_out, int out_size, void* d_ws, size_t ws_size,
                              hipStream_t stream)
{
    (void)in_sizes; (void)n_in; (void)out_size; (void)ws_size;
    const float* fs      = (const float*)d_in[0];
    const float* ft      = (const float*)d_in[1];
    const float* W_embed = (const float*)d_in[2];
    const float* b_embed = (const float*)d_in[3];
    const float* W_gnn   = (const float*)d_in[4];
    const float* b_gnn   = (const float*)d_in[5];
    const float* W_pool  = (const float*)d_in[6];
    const float* b_pool  = (const float*)d_in[7];
    const float* W_gnnp  = (const float*)d_in[8];
    const float* b_gnnp  = (const float*)d_in[9];
    float* out = (float*)d_out;

    float* ws = (float*)d_ws;
    size_t o = 0;
    auto alloc = [&](size_t n) { float* p = ws + o; o += (n + 3) & ~3ull; return p; };
    float* bigB   = alloc(2048ull * 2048);
    float* f_g    = alloc(4096 * 128);
    unsigned short* A01  = (unsigned short*)alloc(2048ull * 2048 / 2);
    unsigned short* feb  = (unsigned short*)alloc(4096ull * 128 / 2);
    unsigned short* febl = (unsigned short*)alloc(4096ull * 128 / 2);
    unsigned short* Xt1  = (unsigned short*)alloc(256ull * 2048 / 2);
    unsigned short* Xt2  = (unsigned short*)alloc(256ull * 2048 / 2);
    unsigned short* f_gb = (unsigned short*)alloc(4096ull * 128 / 2);
    unsigned short* Wtall= (unsigned short*)alloc(5ull * 16384 / 2);
    unsigned short* Ap01 = (unsigned short*)alloc(1024ull * 1024 / 2);
    unsigned short* nhb  = (unsigned short*)alloc(2048ull * 128 / 2);
    unsigned short* Xtp  = (unsigned short*)alloc(256ull * 1024 / 2);
    unsigned short* f_pb = (unsigned short*)alloc(2048ull * 128 / 2);
    float* hW     = alloc(3ull * 4096 * 128);     // hW0 / hW1 / hW2
    float* P0     = alloc(2048ull * 128);         // new_h @ Wp0
    float* dinv   = alloc(2048);
    float* scores = alloc(2048);
    float* vals   = alloc(1024);
    int*   idxb   = (int*)alloc(1024);
    float* dinvp  = alloc(1024);
    unsigned long long* bits = (unsigned long long*)alloc(2048 * 32 * 2);
    float* nceb = alloc(9216);
    int*   deg  = (int*)alloc(2048);
    int*   degp = (int*)alloc(1024);
    const int kZeroCount = 9216 + 2048 + 1024;   // 12288

    const size_t FSTR = 4096ull * 128;
    const size_t PSTR = 1024ull * 256;
    unsigned short* Wt  = Wtall;
    unsigned short* WtP = Wtall + 3ull * 16384;
    float* hW0 = hW;
    float* hW1 = hW + FSTR;
    float* hW2 = hW + 2 * FSTR;
    float* rs  = nceb;
    float* csu = nceb + 2048;
    float* pos = nceb + 4096;
    float* rsp  = nceb + 6144;
    float* csp  = nceb + 7168;
    float* posp = nceb + 8192;

    // 1. embed GEMM (hi/lo MFMA, split-K4) + zero control words + convert weights
    k_setup_embed<<<345, 256, 0, stream>>>(fs, ft, W_embed, bigB, FSTR,
                                           (int*)nceb, kZeroCount, out, W_gnn, W_gnnp, Wtall);
    // 2. embed combine + l2norm -> feb (hi), febl (lo)
    combine_norm<<<4096, 128, 0, stream>>>(bigB, 4, FSTR, b_embed, feb, febl);
    // 3. fused adjacency gram (hi/lo MFMA) + threshold + pack + deg, rider hW
    k_gram_fused<<<720, 256, 0, stream>>>(feb, febl, A01, bits, deg, Wt, hW);
    // 4. Xt1 = (hW2)^T * dinv  (+ dinv)
    make_xt<<<512, 256, 0, stream>>>(hW2, deg, Xt1, dinv);
    // 5. hop1: Y1 = A01 @ Xt1 (split-K 4, 256 blocks)
    mm_bf16<<<dim3(2, 32, 4), 256, 0, stream>>>(A01, 2048, 0, Xt1, 2048, 0,
                                                bigB, 256, FSTR, 512, 512);
    // 6. Xt2 = (hW1 + dinv*Y1)^T * dinv
    reduce_xt<<<dim3(8, 64), 256, 0, stream>>>(bigB, 4, FSTR, 2048, dinv, hW1, Xt2);
    // 7. hop2: Y2 = A01 @ Xt2 (split-K 4)
    mm_bf16<<<dim3(2, 32, 4), 256, 0, stream>>>(A01, 2048, 0, Xt2, 2048, 0,
                                                bigB, 256, FSTR, 512, 512);
    // 8. fused: f_g = l2norm(hW0 + dinv*Y2 + b_gnn), + pooling scores
    combine_tag<<<4096, 128, 0, stream>>>(bigB, 4, FSTR, 2048, hW0, dinv, b_gnn,
                                          f_g, f_gb, W_pool, b_pool, scores);
    // 9. graph NCE gram + topk rider
    k_nce_topk<<<513, 256, 0, stream>>>(f_gb, f_gb + 2048 * 128, rs, csu, pos,
                                        512, 16, scores, vals, idxb);
    // 10. graph NCE finalize + pooled adjacency (32x32 tiles)
    k_final_ap<<<1032, 256, 0, stream>>>(rs, csu, pos, out, bits, idxb, Ap01, degp);
    // 11. gather pooled features (new_h bf16) + dinvp
    gather_nh<<<256, 256, 0, stream>>>(f_g, idxb, vals, degp, nhb, dinvp);
    // 12. pooled linears: P0 = new_h@Wp0; Xtp = (new_h@Wp1)^T * dinvp
    k_lin_pool<<<64, 256, 0, stream>>>(nhb, WtP, dinvp, P0, Xtp);
    // 13. pooled hop: Yp = Ap01 @ Xtp (split-K 4)
    mm_bf16<<<dim3(2, 16, 4), 256, 0, stream>>>(Ap01, 1024, 0, Xtp, 1024, 0,
                                                bigB, 256, PSTR, 256, 256);
    // 14. fused: f_p = l2norm(P0 + dinvp*Yp + b_gnnp)
    combine_tag<<<2048, 128, 0, stream>>>(bigB, 4, PSTR, 1024, P0, dinvp, b_gnnp,
                                          nullptr, f_pb, nullptr, nullptr, nullptr);
    // 15. pooled NCE gram
    k_nce_topk<<<128, 256, 0, stream>>>(f_pb, f_pb + 1024 * 128, rsp, csp, posp,
                                        128, 8, nullptr, nullptr, nullptr);
    // 16. pooled NCE finalize
    nce_final<<<4, 256, 0, stream>>>(rsp, csp, posp, 1.0f / 1024.0f, out);
}